// Round 5
// baseline (238.634 us; speedup 1.0000x reference)
//
#include <hip/hip_runtime.h>
#include <stdint.h>

#define GAMMA 0.002f
#define MDIM 4096
#define NDIM 8192
#define KDIM 512

typedef short v8s __attribute__((ext_vector_type(8)));
typedef float v4f __attribute__((ext_vector_type(4)));

__device__ __forceinline__ unsigned short f32_to_bf16_rne(float f) {
    union { float f; uint32_t u; } v; v.f = f;
    uint32_t u = v.u;
    return (unsigned short)((u + 0x7fffu + ((u >> 16) & 1u)) >> 16);
}

__device__ __forceinline__ void gl_lds16(const void* g, void* l) {
    __builtin_amdgcn_global_load_lds(
        (const __attribute__((address_space(1))) uint32_t*)g,
        (__attribute__((address_space(3))) uint32_t*)l, 16, 0, 0);
}

// One block per row: convert 512 fp32 -> bf16 (RNE) and emit -gamma*sum(x^2).
__global__ __launch_bounds__(256) void convert_rows(
    const float* __restrict__ in, unsigned short* __restrict__ outb,
    float* __restrict__ neg_g_sq) {
    int row = blockIdx.x;
    const float* src = in + (size_t)row * KDIM;
    unsigned short* dst = outb + (size_t)row * KDIM;
    int t = threadIdx.x;
    float2 f = ((const float2*)src)[t];
    ushort2 b;
    b.x = f32_to_bf16_rne(f.x);
    b.y = f32_to_bf16_rne(f.y);
    ((ushort2*)dst)[t] = b;
    float s = f.x * f.x + f.y * f.y;
    #pragma unroll
    for (int off = 32; off > 0; off >>= 1) s += __shfl_down(s, off, 64);
    __shared__ float red[4];
    if ((t & 63) == 0) red[t >> 6] = s;
    __syncthreads();
    if (t == 0) neg_g_sq[row] = -GAMMA * (red[0] + red[1] + red[2] + red[3]);
}

// v4 kernel (unchanged from round 4). Round 5 = measurement probe: the gemm is
// launched TWICE (idempotent, identical output) so that
//   dur_us(round5) - dur_us(round4) = exact gemm duration,
// resolving the fixed-cost vs gemm-cost decomposition that the fill-saturated
// rocprof top-5 hides.
__global__ __launch_bounds__(256, 3) void rbf_gemm(
    const unsigned short* __restrict__ A,   // [4096,512] bf16
    const unsigned short* __restrict__ B,   // [8192,512] bf16
    const float* __restrict__ arow,         // [4096]  = -g*||x||^2
    const float* __restrict__ ccol,         // [8192]  = -g*||sv||^2
    float* __restrict__ out) {

    // LDS: 3 buffers x (A 8 KiB + B 8 KiB) = 48 KiB at 0..49151
    //      sb_r (128 f32) at 49152, sb_c (128 f32) at 49664.  total 50176 B.
    // Epilogue tb [64][128] f32 = 32 KiB reuses 0..32767.
    __shared__ __align__(16) char smem[50176];

    const int tid  = threadIdx.x;
    const int lane = tid & 63;
    const int wave = tid >> 6;          // 0..3
    const int wm   = wave >> 1;         // 0..1 : 64-row slice
    const int wn   = wave & 1;          // 0..1 : 64-col slice

    // bijective XCD swizzle (2048 = 8*256)
    const int bid  = blockIdx.x;
    const int swz  = ((bid & 7) << 8) | (bid >> 3);
    const int row0 = (swz & 31) << 7;   // m tile
    const int col0 = (swz >> 5) << 7;   // n tile

    // ---- staging: tile = [128 rows][32 k] bf16 (64 B/row), rows r=tid>>2 and
    // r+64, 16-B chunk c=tid&3; swizzle byte_col ^= ((r&3)<<4) applied on the
    // GLOBAL source (LDS dest stays linear: tid*16 / +4096).
    const int rS  = tid >> 2;                         // 0..63
    const int cSw = ((tid & 3) << 4) ^ ((rS & 3) << 4);
    const char* aS = (const char*)A + ((size_t)(row0 + rS) << 10) + cSw;
    const char* bS = (const char*)B + ((size_t)(col0 + rS) << 10) + cSw;
    char* dA = smem + tid * 16;
    char* dB = smem + 8192 + tid * 16;

    #define STAGE(t)                                                          \
      do {                                                                    \
        const int _b = ((t) % 3) * 16384;                                     \
        const char* _sa = aS + (t) * 64;                                      \
        const char* _sb = bS + (t) * 64;                                      \
        gl_lds16(_sa,          dA + _b);                                      \
        gl_lds16(_sa + 65536,  dA + _b + 4096);                               \
        gl_lds16(_sb,          dB + _b);                                      \
        gl_lds16(_sb + 65536,  dB + _b + 4096);                               \
      } while (0)

    // ---- fragment addresses (swizzled reads) ----
    const int q   = lane >> 4;          // 0..3 : k-chunk q*8
    const int l15 = lane & 15;
    const int ra0 = wm * 64 + l15;
    const int aOff = ra0 * 64 + (((q << 4)) ^ ((ra0 & 3) << 4));
    const int rb0 = wn * 64 + l15;
    const int bOff = 8192 + rb0 * 64 + (((q << 4)) ^ ((rb0 & 3) << 4));

    v4f acc[4][4];
    #pragma unroll
    for (int i = 0; i < 4; ++i)
        #pragma unroll
        for (int j = 0; j < 4; ++j) acc[i][j] = (v4f)0.0f;

    // prologue: 2 tiles in flight; bias loads; wait tile0 (vmcnt: 8 out, keep 4)
    STAGE(0); STAGE(1);
    if (tid < 128) ((float*)(smem + 49152))[tid] = arow[row0 + tid];
    else           ((float*)(smem + 49664))[tid - 128] = ccol[col0 + tid - 128];
    asm volatile("s_waitcnt vmcnt(4)" ::: "memory");
    __builtin_amdgcn_s_barrier();

    #pragma unroll
    for (int t = 0; t < 16; ++t) {
        if (t + 2 < 16) STAGE(t + 2);
        const int bo = (t % 3) * 16384;
        v8s af[4], bf[4];
        #pragma unroll
        for (int i = 0; i < 4; ++i) af[i] = *(const v8s*)(smem + bo + aOff + i * 1024);
        #pragma unroll
        for (int j = 0; j < 4; ++j) bf[j] = *(const v8s*)(smem + bo + bOff + j * 1024);
        __builtin_amdgcn_s_setprio(1);
        #pragma unroll
        for (int i = 0; i < 4; ++i)
            #pragma unroll
            for (int j = 0; j < 4; ++j)
                acc[i][j] = __builtin_amdgcn_mfma_f32_16x16x32_bf16(
                    bf[j], af[i], acc[i][j], 0, 0, 0);
        __builtin_amdgcn_s_setprio(0);
        if (t < 14)      asm volatile("s_waitcnt vmcnt(4)" ::: "memory");
        else if (t == 14) asm volatile("s_waitcnt vmcnt(0)" ::: "memory");
        __builtin_amdgcn_s_barrier();
    }
    #undef STAGE

    // ---- epilogue: bias+exp in-register, LDS transpose, 512-B row segments
    const float tg = 2.0f * GAMMA;
    const float* sbr = (const float*)(smem + 49152);
    const float* sbc = (const float*)(smem + 49664);
    #pragma unroll
    for (int i = 0; i < 4; ++i) {
        const float ra = sbr[wm * 64 + i * 16 + l15];
        #pragma unroll
        for (int j = 0; j < 4; ++j) {
            #pragma unroll
            for (int v = 0; v < 4; ++v) {
                const int c_l = wn * 64 + j * 16 + (q << 2) + v;
                acc[i][j][v] = __expf(fmaf(tg, acc[i][j][v], ra + sbc[c_l]));
            }
        }
    }

    float* tb = (float*)smem;            // [64][128] f32, granule-XOR swizzled
    #pragma unroll
    for (int ch = 0; ch < 2; ++ch) {
        if (wm == ch) {
            #pragma unroll
            for (int i = 0; i < 4; ++i) {
                const int rl = i * 16 + l15;           // row within chunk
                #pragma unroll
                for (int j = 0; j < 4; ++j) {
                    const int g = wn * 16 + j * 4 + q; // 16-B granule 0..31
                    *(v4f*)&tb[rl * 128 + ((g ^ (rl & 31)) << 2)] = acc[i][j];
                }
            }
        }
        __syncthreads();
        #pragma unroll
        for (int rr = 0; rr < 8; ++rr) {
            const int rl = wave * 16 + (rr << 1) + (lane >> 5);
            v4f val = *(const v4f*)&tb[rl * 128 + (((lane & 31) ^ (rl & 31)) << 2)];
            *(v4f*)(out + (size_t)(row0 + ch * 64 + rl) * NDIM + col0 +
                    ((lane & 31) << 2)) = val;
        }
        __syncthreads();
    }
}

extern "C" void kernel_launch(void* const* d_in, const int* in_sizes, int n_in,
                              void* d_out, int out_size, void* d_ws, size_t ws_size,
                              hipStream_t stream) {
    const float* x  = (const float*)d_in[0];   // [4096,512]
    const float* sv = (const float*)d_in[1];   // [8192,512]
    float* out = (float*)d_out;

    // ws layout: xb (4 MiB) | svb (8 MiB) | arow (16 KiB) | ccol (32 KiB)
    unsigned short* xb  = (unsigned short*)d_ws;
    unsigned short* svb = xb + (size_t)MDIM * KDIM;
    float* arow = (float*)(svb + (size_t)NDIM * KDIM);
    float* ccol = arow + MDIM;

    hipLaunchKernelGGL(convert_rows, dim3(MDIM), dim3(256), 0, stream, x, xb, arow);
    hipLaunchKernelGGL(convert_rows, dim3(NDIM), dim3(256), 0, stream, sv, svb, ccol);
    // Launched twice (idempotent): delta vs round 4 isolates the gemm duration.
    hipLaunchKernelGGL(rbf_gemm, dim3((MDIM / 128) * (NDIM / 128)), dim3(256), 0,
                       stream, xb, svb, arow, ccol, out);
    hipLaunchKernelGGL(rbf_gemm, dim3((MDIM / 128) * (NDIM / 128)), dim3(256), 0,
                       stream, xb, svb, arow, ccol, out);
}

// Round 7
// 183.721 us; speedup vs baseline: 1.2989x; 1.2989x over previous
//
#include <hip/hip_runtime.h>
#include <stdint.h>

#define GAMMA 0.002f
#define MDIM 4096
#define NDIM 8192
#define KDIM 512

typedef short v8s __attribute__((ext_vector_type(8)));
typedef float v4f __attribute__((ext_vector_type(4)));

__device__ __forceinline__ unsigned short f32_to_bf16_rne(float f) {
    union { float f; uint32_t u; } v; v.f = f;
    uint32_t u = v.u;
    return (unsigned short)((u + 0x7fffu + ((u >> 16) & 1u)) >> 16);
}

__device__ __forceinline__ void gl_lds16(const void* g, void* l) {
    __builtin_amdgcn_global_load_lds(
        (const __attribute__((address_space(1))) uint32_t*)g,
        (__attribute__((address_space(3))) uint32_t*)l, 16, 0, 0);
}

// One block per row: convert 512 fp32 -> bf16 (RNE) and emit -gamma*sum(x^2).
__global__ __launch_bounds__(256) void convert_rows(
    const float* __restrict__ in, unsigned short* __restrict__ outb,
    float* __restrict__ neg_g_sq) {
    int row = blockIdx.x;
    const float* src = in + (size_t)row * KDIM;
    unsigned short* dst = outb + (size_t)row * KDIM;
    int t = threadIdx.x;
    float2 f = ((const float2*)src)[t];
    ushort2 b;
    b.x = f32_to_bf16_rne(f.x);
    b.y = f32_to_bf16_rne(f.y);
    ((ushort2*)dst)[t] = b;
    float s = f.x * f.x + f.y * f.y;
    #pragma unroll
    for (int off = 32; off > 0; off >>= 1) s += __shfl_down(s, off, 64);
    __shared__ float red[4];
    if ((t & 63) == 0) red[t >> 6] = s;
    __syncthreads();
    if (t == 0) neg_g_sq[row] = -GAMMA * (red[0] + red[1] + red[2] + red[3]);
}

// v5: identical schedule/epilogue to v4 (round 4, gemm = 51.7 us measured).
// ONE change: L2-aware XCD partition. Each XCD owns a 16m x 16n tile region
// (2 MiB A + 2 MiB B = per-XCD L2 capacity), m fastest within region,
// eliminating the A-panel L2 thrash of the previous all-m x 8n mapping.
__global__ __launch_bounds__(256, 3) void rbf_gemm(
    const unsigned short* __restrict__ A,   // [4096,512] bf16
    const unsigned short* __restrict__ B,   // [8192,512] bf16
    const float* __restrict__ arow,         // [4096]  = -g*||x||^2
    const float* __restrict__ ccol,         // [8192]  = -g*||sv||^2
    float* __restrict__ out) {

    // LDS: 3 buffers x (A 8 KiB + B 8 KiB) = 48 KiB at 0..49151
    //      sb_r (128 f32) at 49152, sb_c (128 f32) at 49664.  total 50176 B.
    __shared__ __align__(16) char smem[50176];

    const int tid  = threadIdx.x;
    const int lane = tid & 63;
    const int wave = tid >> 6;          // 0..3
    const int wm   = wave >> 1;         // 0..1 : 64-row slice
    const int wn   = wave & 1;          // 0..1 : 64-col slice

    // L2-aware partition: xcd = bid&7 (round-robin dispatch), region 16m x 16n.
    const int bid = blockIdx.x;
    const int xcd = bid & 7;
    const int idx = bid >> 3;                       // 0..255 within region
    const int mt  = ((xcd & 1) << 4) | (idx & 15);  // 0..31
    const int nt  = ((xcd >> 1) << 4) | (idx >> 4); // 0..63
    const int row0 = mt << 7;
    const int col0 = nt << 7;

    // ---- staging: tile = [128 rows][32 k] bf16 (64 B/row), rows r=tid>>2 and
    // r+64, 16-B chunk c=tid&3; swizzle byte_col ^= ((r&3)<<4) applied on the
    // GLOBAL source (LDS dest stays linear: tid*16 / +4096).
    const int rS  = tid >> 2;                         // 0..63
    const int cSw = ((tid & 3) << 4) ^ ((rS & 3) << 4);
    const char* aS = (const char*)A + ((size_t)(row0 + rS) << 10) + cSw;
    const char* bS = (const char*)B + ((size_t)(col0 + rS) << 10) + cSw;
    char* dA = smem + tid * 16;
    char* dB = smem + 8192 + tid * 16;

    #define STAGE(t)                                                          \
      do {                                                                    \
        const int _b = ((t) % 3) * 16384;                                     \
        const char* _sa = aS + (t) * 64;                                      \
        const char* _sb = bS + (t) * 64;                                      \
        gl_lds16(_sa,          dA + _b);                                      \
        gl_lds16(_sa + 65536,  dA + _b + 4096);                               \
        gl_lds16(_sb,          dB + _b);                                      \
        gl_lds16(_sb + 65536,  dB + _b + 4096);                               \
      } while (0)

    // ---- fragment addresses (swizzled reads) ----
    const int q   = lane >> 4;          // 0..3 : k-chunk q*8
    const int l15 = lane & 15;
    const int ra0 = wm * 64 + l15;
    const int aOff = ra0 * 64 + (((q << 4)) ^ ((ra0 & 3) << 4));
    const int rb0 = wn * 64 + l15;
    const int bOff = 8192 + rb0 * 64 + (((q << 4)) ^ ((rb0 & 3) << 4));

    v4f acc[4][4];
    #pragma unroll
    for (int i = 0; i < 4; ++i)
        #pragma unroll
        for (int j = 0; j < 4; ++j) acc[i][j] = (v4f)0.0f;

    // prologue: 2 tiles in flight; bias loads; wait tile0 (vmcnt: 8 out, keep 4)
    STAGE(0); STAGE(1);
    if (tid < 128) ((float*)(smem + 49152))[tid] = arow[row0 + tid];
    else           ((float*)(smem + 49664))[tid - 128] = ccol[col0 + tid - 128];
    asm volatile("s_waitcnt vmcnt(4)" ::: "memory");
    __builtin_amdgcn_s_barrier();

    #pragma unroll
    for (int t = 0; t < 16; ++t) {
        if (t + 2 < 16) STAGE(t + 2);
        const int bo = (t % 3) * 16384;
        v8s af[4], bf[4];
        #pragma unroll
        for (int i = 0; i < 4; ++i) af[i] = *(const v8s*)(smem + bo + aOff + i * 1024);
        #pragma unroll
        for (int j = 0; j < 4; ++j) bf[j] = *(const v8s*)(smem + bo + bOff + j * 1024);
        __builtin_amdgcn_s_setprio(1);
        #pragma unroll
        for (int i = 0; i < 4; ++i)
            #pragma unroll
            for (int j = 0; j < 4; ++j)
                acc[i][j] = __builtin_amdgcn_mfma_f32_16x16x32_bf16(
                    bf[j], af[i], acc[i][j], 0, 0, 0);
        __builtin_amdgcn_s_setprio(0);
        if (t < 14)      asm volatile("s_waitcnt vmcnt(4)" ::: "memory");
        else if (t == 14) asm volatile("s_waitcnt vmcnt(0)" ::: "memory");
        __builtin_amdgcn_s_barrier();
    }
    #undef STAGE

    // ---- epilogue: bias+exp in-register, LDS transpose, 512-B row segments
    const float tg = 2.0f * GAMMA;
    const float* sbr = (const float*)(smem + 49152);
    const float* sbc = (const float*)(smem + 49664);
    #pragma unroll
    for (int i = 0; i < 4; ++i) {
        const float ra = sbr[wm * 64 + i * 16 + l15];
        #pragma unroll
        for (int j = 0; j < 4; ++j) {
            #pragma unroll
            for (int v = 0; v < 4; ++v) {
                const int c_l = wn * 64 + j * 16 + (q << 2) + v;
                acc[i][j][v] = __expf(fmaf(tg, acc[i][j][v], ra + sbc[c_l]));
            }
        }
    }

    float* tb = (float*)smem;            // [64][128] f32, granule-XOR swizzled
    #pragma unroll
    for (int ch = 0; ch < 2; ++ch) {
        if (wm == ch) {
            #pragma unroll
            for (int i = 0; i < 4; ++i) {
                const int rl = i * 16 + l15;           // row within chunk
                #pragma unroll
                for (int j = 0; j < 4; ++j) {
                    const int g = wn * 16 + j * 4 + q; // 16-B granule 0..31
                    *(v4f*)&tb[rl * 128 + ((g ^ (rl & 31)) << 2)] = acc[i][j];
                }
            }
        }
        __syncthreads();
        #pragma unroll
        for (int rr = 0; rr < 8; ++rr) {
            const int rl = wave * 16 + (rr << 1) + (lane >> 5);
            v4f val = *(const v4f*)&tb[rl * 128 + (((lane & 31) ^ (rl & 31)) << 2)];
            *(v4f*)(out + (size_t)(row0 + ch * 64 + rl) * NDIM + col0 +
                    ((lane & 31) << 2)) = val;
        }
        __syncthreads();
    }
}

extern "C" void kernel_launch(void* const* d_in, const int* in_sizes, int n_in,
                              void* d_out, int out_size, void* d_ws, size_t ws_size,
                              hipStream_t stream) {
    const float* x  = (const float*)d_in[0];   // [4096,512]
    const float* sv = (const float*)d_in[1];   // [8192,512]
    float* out = (float*)d_out;

    // ws layout: xb (4 MiB) | svb (8 MiB) | arow (16 KiB) | ccol (32 KiB)
    unsigned short* xb  = (unsigned short*)d_ws;
    unsigned short* svb = xb + (size_t)MDIM * KDIM;
    float* arow = (float*)(svb + (size_t)NDIM * KDIM);
    float* ccol = arow + MDIM;

    hipLaunchKernelGGL(convert_rows, dim3(MDIM), dim3(256), 0, stream, x, xb, arow);
    hipLaunchKernelGGL(convert_rows, dim3(NDIM), dim3(256), 0, stream, sv, svb, ccol);
    hipLaunchKernelGGL(rbf_gemm, dim3((MDIM / 128) * (NDIM / 128)), dim3(256), 0,
                       stream, xb, svb, arow, ccol, out);
}